// Round 6
// baseline (288.383 us; speedup 1.0000x reference)
//
#include <hip/hip_runtime.h>
#include <hip/hip_bf16.h>
#include <float.h>

#define F_DIM 64
#define H_DIM 128
#define LW2   104   // wt2 row stride (bf16) for K=96 [x[e0]|ppf|pad]: 208 B, 16B-aligned
#define LW1   72    // w1t row stride (bf16) for K=64 [x[e1]]: 144 B, 16B-aligned

typedef __attribute__((ext_vector_type(8))) short short8;   // 8 bf16 (mfma A/B frag)
typedef __attribute__((ext_vector_type(4))) float f32x4;    // mfma C/D frag

__device__ __forceinline__ unsigned short f2bf(float f) {
    __hip_bfloat16 h = __float2bfloat16(f);
    return __builtin_bit_cast(unsigned short, h);
}
__device__ __forceinline__ unsigned pk(float a, float b) {
    return (unsigned)f2bf(a) | ((unsigned)f2bf(b) << 16);
}

__device__ __forceinline__ float angle3(float ax, float ay, float az,
                                        float bx, float by, float bz) {
    float cx = ay*bz - az*by;
    float cy = az*bx - ax*bz;
    float cz = ax*by - ay*bx;
    float cn = sqrtf(cx*cx + cy*cy + cz*cz);
    float d  = ax*bx + ay*by + az*bz;
    return atan2f(cn, d);
}

// fused streaming pass: wt2 + w1t builds, xbf (x->bf16 mfma layout), node2slot scatter,
// per-NODE edge histogram with rank capture (atomic return is the free rank), pos tail.
// cnt_node must be zeroed (hipMemsetAsync) before this kernel.
__global__ __launch_bounds__(256)
void prep0(const float* __restrict__ W, unsigned short* __restrict__ wt2,
           unsigned short* __restrict__ w1t, const float* __restrict__ x,
           unsigned short* __restrict__ xbf, const int* __restrict__ idx,
           int* __restrict__ node2slot, const int* __restrict__ edge,
           int* __restrict__ cnt_node, unsigned short* __restrict__ rank16,
           const float* __restrict__ pos, float* __restrict__ out,
           int S, int E, int NF8) {
    const int T = gridDim.x * blockDim.x;
    const int gid = blockIdx.x * blockDim.x + threadIdx.x;
    for (int g = gid; g < NF8; g += T) {                  // x[N][64] f32 -> bf16, 8/thread
        const float4* s4 = (const float4*)x + (size_t)g * 2;
        float4 f0 = s4[0], f1 = s4[1];
        uint4 q;
        q.x = pk(f0.x, f0.y); q.y = pk(f0.z, f0.w);
        q.z = pk(f1.x, f1.y); q.w = pk(f1.z, f1.w);
        ((uint4*)xbf)[g] = q;
    }
    for (int g = gid; g < H_DIM * LW2; g += T) {          // W rows 64..131 -> [H][LW2]
        int h = g / LW2, k = g % LW2;
        float v = 0.f;
        if (k < F_DIM)          v = W[(F_DIM + k) * H_DIM + h];
        else if (k < F_DIM + 4) v = W[(2 * F_DIM + (k - F_DIM)) * H_DIM + h];
        wt2[g] = f2bf(v);
    }
    for (int g = gid; g < H_DIM * LW1; g += T) {          // W rows 0..63 -> [H][LW1]
        int h = g / LW1, k = g % LW1;
        w1t[g] = f2bf((k < F_DIM) ? W[k * H_DIM + h] : 0.f);
    }
    for (int g = gid; g < S; g += T) node2slot[idx[g]] = g;  // any winner = canonical slot
    for (int g = gid; g < E; g += T) {                       // per-node histogram + rank
        int e1 = edge[E + g];
        rank16[g] = (unsigned short)atomicAdd(&cnt_node[e1], 1);
    }
    for (int g = gid; g < 3 * S; g += T)                     // out tail = pos[idx]
        out[(size_t)S * H_DIM + g] = pos[(size_t)idx[g / 3] * 3 + (g % 3)];
}

// blocks [0,AB): per-slot range alloc (n from cnt_node with canonical check) -> off, ns.
// blocks [AB,AB+CB): cmat = b + x[idx]·W1 -> out
__global__ __launch_bounds__(256)
void alloc_cmat(const int* __restrict__ cnt_node, const int* __restrict__ node2slot,
                int* __restrict__ off, int* __restrict__ ns, int* __restrict__ total,
                const unsigned short* __restrict__ xbf,
                const unsigned short* __restrict__ w1t, const float* __restrict__ bias,
                const int* __restrict__ idx, float* __restrict__ out, int S, int AB) {
    __shared__ int wsum[4];
    __shared__ int bb;
    __shared__ __align__(16) unsigned short a_lds[64 * LW1];
    const int tid = threadIdx.x;

    if ((int)blockIdx.x < AB) {
        int s = blockIdx.x * 256 + tid;
        int v = 0;
        if (s < S) {
            int node = idx[s];
            if (node2slot[node] == s) v = cnt_node[node];   // non-canonical dup slot -> 0
        }
        int lane = tid & 63, wv = tid >> 6;
        int sc = v;
        #pragma unroll
        for (int d = 1; d < 64; d <<= 1) {
            int t = __shfl_up(sc, d, 64);
            if (lane >= d) sc += t;
        }
        if (lane == 63) wsum[wv] = sc;
        __syncthreads();
        if (tid == 0) {
            int t = 0;
            #pragma unroll
            for (int i = 0; i < 4; ++i) { int w = wsum[i]; wsum[i] = t; t += w; }
            bb = atomicAdd(total, t);
        }
        __syncthreads();
        int excl = bb + wsum[wv] + sc - v;
        if (s < S) { off[s] = excl; ns[s] = v; }
        return;
    }

    // ---- cmat: 64 slots per block, A rows from xbf (already bf16) ----
    const int sbase = (blockIdx.x - AB) * 64;
    const int m = tid >> 2, p = tid & 3;
    {
        int s = sbase + m; if (s >= S) s = S - 1;
        int node = idx[s];
        const uint4* src = (const uint4*)(xbf + (size_t)node * F_DIM) + p * 2;
        uint4* dst = (uint4*)(a_lds + m * LW1 + p * 16);
        dst[0] = src[0]; dst[1] = src[1];
        if (p == 0) *(uint4*)(a_lds + m * LW1 + 64) = make_uint4(0, 0, 0, 0);
    }
    __syncthreads();
    const int wv = tid >> 6, lane = tid & 63, l15 = lane & 15, quad = lane >> 4;
    const int n0 = wv * 32 + l15, n1 = n0 + 16;
    f32x4 acc[4][2];
    #pragma unroll
    for (int i = 0; i < 4; ++i) {
        acc[i][0] = (f32x4){0.f, 0.f, 0.f, 0.f};
        acc[i][1] = (f32x4){0.f, 0.f, 0.f, 0.f};
    }
    #pragma unroll
    for (int ks = 0; ks < 2; ++ks) {
        const int ko = ks * 32 + quad * 8;
        short8 bf0 = *(const short8*)(w1t + (size_t)n0 * LW1 + ko);
        short8 bf1 = *(const short8*)(w1t + (size_t)n1 * LW1 + ko);
        #pragma unroll
        for (int mt = 0; mt < 4; ++mt) {
            short8 af = *(const short8*)(a_lds + (mt * 16 + l15) * LW1 + ko);
            acc[mt][0] = __builtin_amdgcn_mfma_f32_16x16x32_bf16(af, bf0, acc[mt][0], 0, 0, 0);
            acc[mt][1] = __builtin_amdgcn_mfma_f32_16x16x32_bf16(af, bf1, acc[mt][1], 0, 0, 0);
        }
    }
    const float b0 = bias[n0], b1 = bias[n1];
    #pragma unroll
    for (int mt = 0; mt < 4; ++mt) {
        #pragma unroll
        for (int r = 0; r < 4; ++r) {
            int s = sbase + mt * 16 + quad * 4 + r;     // C/D: row = quad*4 + reg
            if (s < S) {
                out[(size_t)s * H_DIM + n0] = acc[mt][0][r] + b0;
                out[(size_t)s * H_DIM + n1] = acc[mt][1][r] + b1;
            }
        }
    }
}

// ATOMIC-FREE placement: p = off[slot(e1)] + rank[e]; gathers + trig + one 16B record write.
// Runs at full occupancy -> all latency hidden here, off seg's critical chain.
__global__ void place_kernel(const int* __restrict__ edge, const float* __restrict__ pos,
                             const float* __restrict__ normal,
                             const int* __restrict__ node2slot,
                             const unsigned short* __restrict__ rank16,
                             const int* __restrict__ off, uint4* __restrict__ prec, int E) {
    int e = blockIdx.x * blockDim.x + threadIdx.x;
    if (e >= E) return;
    int e0 = edge[e], e1 = edge[E + e];
    int p = off[node2slot[e1]] + (int)rank16[e];
    float px = pos[3 * e0]     - pos[3 * e1];
    float py = pos[3 * e0 + 1] - pos[3 * e1 + 1];
    float pz = pos[3 * e0 + 2] - pos[3 * e1 + 2];
    float n0x = normal[3 * e0], n0y = normal[3 * e0 + 1], n0z = normal[3 * e0 + 2];
    float n1x = normal[3 * e1], n1y = normal[3 * e1 + 1], n1z = normal[3 * e1 + 2];
    float d  = sqrtf(px * px + py * py + pz * pz);
    float a1 = angle3(n1x, n1y, n1z, px, py, pz);
    float a2 = angle3(n0x, n0y, n0z, px, py, pz);
    float a3 = angle3(n1x, n1y, n1z, n0x, n0y, n0z);
    uint4 rec;
    rec.x = (unsigned)e0;
    rec.y = pk(d, a1);
    rec.z = pk(a2, a3);
    rec.w = 0;
    prec[p] = rec;
}

__device__ __forceinline__ void load_af(uint4 rec, const unsigned short* __restrict__ xbf,
                                        int quad, short8& a0, short8& a1, short8& a2) {
    const short8* xr = (const short8*)(xbf + (size_t)rec.x * F_DIM);
    a0 = xr[quad];          // k = quad*8 .. +8
    a1 = xr[4 + quad];      // k = 32 + quad*8 .. +8
    short8 z = (short8){0, 0, 0, 0, 0, 0, 0, 0};
    if (quad == 0) {        // k = 64..67 = ppf, 68..71 zero (wt2 rows 68+ are zero anyway)
        z[0] = (short)(rec.y & 0xffff); z[1] = (short)(rec.y >> 16);
        z[2] = (short)(rec.z & 0xffff); z[3] = (short)(rec.z >> 16);
    }
    a2 = z;
}

// wave-per-segment: A from prec/xbf (no conversion, no trig), W2 in LDS staged once/block,
// software-pipelined tile loop, out row = relu(c + max) RMW (c written by cmat)
__global__ __launch_bounds__(256, 4)
void seg_kernel(const unsigned short* __restrict__ xbf, const unsigned short* __restrict__ wt2,
                const uint4* __restrict__ prec, const int* __restrict__ off,
                const int* __restrict__ ns, float* __restrict__ out, int S) {
    __shared__ __align__(16) unsigned short w_lds[H_DIM * LW2];
    {
        const uint4* src = (const uint4*)wt2;
        uint4* dst = (uint4*)w_lds;
        for (int g = threadIdx.x; g < H_DIM * LW2 / 8; g += 256) dst[g] = src[g];
    }
    __syncthreads();

    const int tid  = threadIdx.x;
    const int wv   = tid >> 6;
    const int lane = tid & 63;
    const int l15  = lane & 15;
    const int quad = lane >> 4;
    const int nw   = gridDim.x << 2;

    for (int s = (blockIdx.x << 2) + wv; s < S; s += nw) {
        const int n = ns[s];
        float* orow = out + (size_t)s * H_DIM;
        if (n == 0) {                   // empty segment or non-canonical duplicate slot
            orow[lane] = 0.f;
            orow[64 + lane] = 0.f;
            continue;
        }
        const uint4* pb = prec + off[s];

        float rm[8];
        #pragma unroll
        for (int ct = 0; ct < 8; ++ct) rm[ct] = -FLT_MAX;

        const int ntile = (n + 15) >> 4;
        int r = l15; if (r >= n) r = n - 1;           // pad rows = real edge dup -> exact for max
        uint4 rec = pb[r];
        short8 a0c, a1c, a2c;
        load_af(rec, xbf, quad, a0c, a1c, a2c);

        for (int t = 0; t < ntile; ++t) {
            // prefetch next tile's record + A-frags (overlaps the MFMAs below)
            uint4 recn = rec;
            if (t + 1 < ntile) {
                int rn = ((t + 1) << 4) + l15; if (rn >= n) rn = n - 1;
                recn = pb[rn];
            }
            short8 a0n, a1n, a2n;
            load_af(recn, xbf, quad, a0n, a1n, a2n);

            f32x4 acc[8];
            #pragma unroll
            for (int ct = 0; ct < 8; ++ct) acc[ct] = (f32x4){0.f, 0.f, 0.f, 0.f};
            #pragma unroll
            for (int ct = 0; ct < 8; ++ct) {
                const unsigned short* wc = w_lds + (ct * 16 + l15) * LW2 + (quad << 3);
                short8 b0 = *(const short8*)(wc);
                short8 b1 = *(const short8*)(wc + 32);
                short8 b2 = *(const short8*)(wc + 64);
                acc[ct] = __builtin_amdgcn_mfma_f32_16x16x32_bf16(a0c, b0, acc[ct], 0, 0, 0);
                acc[ct] = __builtin_amdgcn_mfma_f32_16x16x32_bf16(a1c, b1, acc[ct], 0, 0, 0);
                acc[ct] = __builtin_amdgcn_mfma_f32_16x16x32_bf16(a2c, b2, acc[ct], 0, 0, 0);
            }
            #pragma unroll
            for (int ct = 0; ct < 8; ++ct)
                rm[ct] = fmaxf(rm[ct], fmaxf(fmaxf(acc[ct][0], acc[ct][1]),
                                             fmaxf(acc[ct][2], acc[ct][3])));
            a0c = a0n; a1c = a1n; a2c = a2n; rec = recn;
        }

        #pragma unroll
        for (int ct = 0; ct < 8; ++ct) {
            rm[ct] = fmaxf(rm[ct], __shfl_xor(rm[ct], 16, 64));
            rm[ct] = fmaxf(rm[ct], __shfl_xor(rm[ct], 32, 64));
        }
        float v0 = rm[0], v1 = rm[4];   // col = ct*16 + l15; lane writes cols lane, lane+64
        if (quad == 1)      { v0 = rm[1]; v1 = rm[5]; }
        else if (quad == 2) { v0 = rm[2]; v1 = rm[6]; }
        else if (quad == 3) { v0 = rm[3]; v1 = rm[7]; }
        orow[lane]      = fmaxf(orow[lane] + v0, 0.f);        // c + max, relu (hoist exact)
        orow[64 + lane] = fmaxf(orow[64 + lane] + v1, 0.f);
    }
}

// duplicate-idx fixup only (pos tail handled by prep0)
__global__ void finalize(const int* __restrict__ idx, const int* __restrict__ node2slot,
                         float* __restrict__ out, int S) {
    int g = blockIdx.x * blockDim.x + threadIdx.x;
    if (g >= S * H_DIM) return;
    int s = g >> 7, c = g & 127;
    int sp = node2slot[idx[s]];
    if (sp != s) out[g] = out[(size_t)sp * H_DIM + c];
}

extern "C" void kernel_launch(void* const* d_in, const int* in_sizes, int n_in,
                              void* d_out, int out_size, void* d_ws, size_t ws_size,
                              hipStream_t stream) {
    const float* x      = (const float*)d_in[0];
    const float* pos    = (const float*)d_in[1];
    const float* normal = (const float*)d_in[2];
    const float* W      = (const float*)d_in[3];
    const float* b      = (const float*)d_in[4];
    const int*   edge   = (const int*)d_in[5];
    const int*   idx    = (const int*)d_in[6];

    const int H = in_sizes[4];            // 128
    const int K = in_sizes[3] / H;        // 132
    const int F = (K - 4) / 2;            // 64
    const int N = in_sizes[0] / F;        // 100000
    const int E = in_sizes[5] / 2;        // 800000
    const int S = in_sizes[6];            // 25000

    // ws (256B aligned): wt2 | w1t | xbf[N*64]bf16 | prec[E]uint4 | node2slot[N]
    //                    | cnt_node[N+1] (last int = total) | rank16[E] | off[S] | ns[S]
    char* p = (char*)d_ws;
    auto alloc = [&](size_t bytes) { char* r = p; p += (bytes + 255) & ~(size_t)255; return r; };
    unsigned short* wt2 = (unsigned short*)alloc((size_t)H_DIM * LW2 * sizeof(unsigned short));
    unsigned short* w1t = (unsigned short*)alloc((size_t)H_DIM * LW1 * sizeof(unsigned short));
    unsigned short* xbf = (unsigned short*)alloc((size_t)N * F_DIM * sizeof(unsigned short));
    uint4* prec         = (uint4*)alloc((size_t)E * sizeof(uint4));
    int* node2slot      = (int*)alloc((size_t)N * sizeof(int));
    int* cnt_node       = (int*)alloc((size_t)(N + 1) * sizeof(int));
    unsigned short* rank16 = (unsigned short*)alloc((size_t)E * sizeof(unsigned short));
    int* off            = (int*)alloc((size_t)S * sizeof(int));
    int* ns             = (int*)alloc((size_t)S * sizeof(int));
    float* out = (float*)d_out;           // cmat writes c, seg RMWs to final result

    const int AB = (S + 255) / 256;
    const int CB = (S + 63) / 64;
    const int NF8 = N * F_DIM / 8;

    hipMemsetAsync(cnt_node, 0, (size_t)(N + 1) * sizeof(int), stream);
    prep0<<<1024, 256, 0, stream>>>(W, wt2, w1t, x, xbf, idx, node2slot, edge,
                                    cnt_node, rank16, pos, out, S, E, NF8);
    alloc_cmat<<<AB + CB, 256, 0, stream>>>(cnt_node, node2slot, off, ns, cnt_node + N,
                                            xbf, w1t, b, idx, out, S, AB);
    place_kernel<<<(E + 255) / 256, 256, 0, stream>>>(edge, pos, normal, node2slot,
                                                      rank16, off, prec, E);
    seg_kernel<<<3072, 256, 0, stream>>>(xbf, wt2, prec, off, ns, out, S);
    finalize<<<(S * H + 255) / 256, 256, 0, stream>>>(idx, node2slot, out, S);
}

// Round 7
// 220.172 us; speedup vs baseline: 1.3098x; 1.3098x over previous
//
#include <hip/hip_runtime.h>
#include <hip/hip_bf16.h>
#include <float.h>

#define F_DIM 64
#define H_DIM 128
#define LW2   104   // wt2 row stride (bf16) for K=96 [x[e0]|ppf|pad]: 208 B, 16B-aligned
#define LW1   72    // w1t row stride (bf16) for K=64 [x[e1]]: 144 B, 16B-aligned

typedef __attribute__((ext_vector_type(8))) short short8;   // 8 bf16 (mfma A/B frag)
typedef __attribute__((ext_vector_type(4))) float f32x4;    // mfma C/D frag

__device__ __forceinline__ unsigned short f2bf(float f) {
    __hip_bfloat16 h = __float2bfloat16(f);
    return __builtin_bit_cast(unsigned short, h);
}
__device__ __forceinline__ unsigned pk(float a, float b) {
    return (unsigned)f2bf(a) | ((unsigned)f2bf(b) << 16);
}

__device__ __forceinline__ float angle3(float ax, float ay, float az,
                                        float bx, float by, float bz) {
    float cx = ay*bz - az*by;
    float cy = az*bx - ax*bz;
    float cz = ax*by - ay*bx;
    float cn = sqrtf(cx*cx + cy*cy + cz*cz);
    float d  = ax*bx + ay*by + az*bz;
    return atan2f(cn, d);
}

// fused streaming pass: wt2 + w1t builds, xbf (x->bf16 mfma layout), node2slot scatter,
// per-NODE edge histogram with rank capture (atomic return is the free rank), pos tail.
// cnt_node must be zeroed (hipMemsetAsync) before this kernel.
__global__ __launch_bounds__(256)
void prep0(const float* __restrict__ W, unsigned short* __restrict__ wt2,
           unsigned short* __restrict__ w1t, const float* __restrict__ x,
           unsigned short* __restrict__ xbf, const int* __restrict__ idx,
           int* __restrict__ node2slot, const int* __restrict__ edge,
           int* __restrict__ cnt_node, unsigned short* __restrict__ rank16,
           const float* __restrict__ pos, float* __restrict__ out,
           int S, int E, int NF8) {
    const int T = gridDim.x * blockDim.x;
    const int gid = blockIdx.x * blockDim.x + threadIdx.x;
    for (int g = gid; g < NF8; g += T) {                  // x[N][64] f32 -> bf16, 8/thread
        const float4* s4 = (const float4*)x + (size_t)g * 2;
        float4 f0 = s4[0], f1 = s4[1];
        uint4 q;
        q.x = pk(f0.x, f0.y); q.y = pk(f0.z, f0.w);
        q.z = pk(f1.x, f1.y); q.w = pk(f1.z, f1.w);
        ((uint4*)xbf)[g] = q;
    }
    for (int g = gid; g < H_DIM * LW2; g += T) {          // W rows 64..131 -> [H][LW2]
        int h = g / LW2, k = g % LW2;
        float v = 0.f;
        if (k < F_DIM)          v = W[(F_DIM + k) * H_DIM + h];
        else if (k < F_DIM + 4) v = W[(2 * F_DIM + (k - F_DIM)) * H_DIM + h];
        wt2[g] = f2bf(v);
    }
    for (int g = gid; g < H_DIM * LW1; g += T) {          // W rows 0..63 -> [H][LW1]
        int h = g / LW1, k = g % LW1;
        w1t[g] = f2bf((k < F_DIM) ? W[k * H_DIM + h] : 0.f);
    }
    for (int g = gid; g < S; g += T) node2slot[idx[g]] = g;  // any winner = canonical slot
    for (int g = gid; g < E; g += T) {                       // per-node histogram + rank
        int e1 = edge[E + g];
        rank16[g] = (unsigned short)atomicAdd(&cnt_node[e1], 1);
    }
    for (int g = gid; g < 3 * S; g += T)                     // out tail = pos[idx]
        out[(size_t)S * H_DIM + g] = pos[(size_t)idx[g / 3] * 3 + (g % 3)];
}

// blocks [0,AB): per-slot range alloc (n from cnt_node with canonical check) -> off, ns.
// blocks [AB,AB+CB): cmat = b + x[idx]·W1 -> out
__global__ __launch_bounds__(256)
void alloc_cmat(const int* __restrict__ cnt_node, const int* __restrict__ node2slot,
                int* __restrict__ off, int* __restrict__ ns, int* __restrict__ total,
                const unsigned short* __restrict__ xbf,
                const unsigned short* __restrict__ w1t, const float* __restrict__ bias,
                const int* __restrict__ idx, float* __restrict__ out, int S, int AB) {
    __shared__ int wsum[4];
    __shared__ int bb;
    __shared__ __align__(16) unsigned short a_lds[64 * LW1];
    const int tid = threadIdx.x;

    if ((int)blockIdx.x < AB) {
        int s = blockIdx.x * 256 + tid;
        int v = 0;
        if (s < S) {
            int node = idx[s];
            if (node2slot[node] == s) v = cnt_node[node];   // non-canonical dup slot -> 0
        }
        int lane = tid & 63, wv = tid >> 6;
        int sc = v;
        #pragma unroll
        for (int d = 1; d < 64; d <<= 1) {
            int t = __shfl_up(sc, d, 64);
            if (lane >= d) sc += t;
        }
        if (lane == 63) wsum[wv] = sc;
        __syncthreads();
        if (tid == 0) {
            int t = 0;
            #pragma unroll
            for (int i = 0; i < 4; ++i) { int w = wsum[i]; wsum[i] = t; t += w; }
            bb = atomicAdd(total, t);
        }
        __syncthreads();
        int excl = bb + wsum[wv] + sc - v;
        if (s < S) { off[s] = excl; ns[s] = v; }
        return;
    }

    // ---- cmat: 64 slots per block, A rows from xbf (already bf16) ----
    const int sbase = (blockIdx.x - AB) * 64;
    const int m = tid >> 2, p = tid & 3;
    {
        int s = sbase + m; if (s >= S) s = S - 1;
        int node = idx[s];
        const uint4* src = (const uint4*)(xbf + (size_t)node * F_DIM) + p * 2;
        uint4* dst = (uint4*)(a_lds + m * LW1 + p * 16);
        dst[0] = src[0]; dst[1] = src[1];
        if (p == 0) *(uint4*)(a_lds + m * LW1 + 64) = make_uint4(0, 0, 0, 0);
    }
    __syncthreads();
    const int wv = tid >> 6, lane = tid & 63, l15 = lane & 15, quad = lane >> 4;
    const int n0 = wv * 32 + l15, n1 = n0 + 16;
    f32x4 acc[4][2];
    #pragma unroll
    for (int i = 0; i < 4; ++i) {
        acc[i][0] = (f32x4){0.f, 0.f, 0.f, 0.f};
        acc[i][1] = (f32x4){0.f, 0.f, 0.f, 0.f};
    }
    #pragma unroll
    for (int ks = 0; ks < 2; ++ks) {
        const int ko = ks * 32 + quad * 8;
        short8 bf0 = *(const short8*)(w1t + (size_t)n0 * LW1 + ko);
        short8 bf1 = *(const short8*)(w1t + (size_t)n1 * LW1 + ko);
        #pragma unroll
        for (int mt = 0; mt < 4; ++mt) {
            short8 af = *(const short8*)(a_lds + (mt * 16 + l15) * LW1 + ko);
            acc[mt][0] = __builtin_amdgcn_mfma_f32_16x16x32_bf16(af, bf0, acc[mt][0], 0, 0, 0);
            acc[mt][1] = __builtin_amdgcn_mfma_f32_16x16x32_bf16(af, bf1, acc[mt][1], 0, 0, 0);
        }
    }
    const float b0 = bias[n0], b1 = bias[n1];
    #pragma unroll
    for (int mt = 0; mt < 4; ++mt) {
        #pragma unroll
        for (int r = 0; r < 4; ++r) {
            int s = sbase + mt * 16 + quad * 4 + r;     // C/D: row = quad*4 + reg
            if (s < S) {
                out[(size_t)s * H_DIM + n0] = acc[mt][0][r] + b0;
                out[(size_t)s * H_DIM + n1] = acc[mt][1][r] + b1;
            }
        }
    }
}

// ATOMIC-FREE placement: p = off[slot(e1)] + rank[e]; gathers + trig + one 16B record write.
// Runs at full occupancy -> all latency hidden here, off seg's critical chain.
__global__ void place_kernel(const int* __restrict__ edge, const float* __restrict__ pos,
                             const float* __restrict__ normal,
                             const int* __restrict__ node2slot,
                             const unsigned short* __restrict__ rank16,
                             const int* __restrict__ off, uint4* __restrict__ prec, int E) {
    int e = blockIdx.x * blockDim.x + threadIdx.x;
    if (e >= E) return;
    int e0 = edge[e], e1 = edge[E + e];
    int p = off[node2slot[e1]] + (int)rank16[e];
    float px = pos[3 * e0]     - pos[3 * e1];
    float py = pos[3 * e0 + 1] - pos[3 * e1 + 1];
    float pz = pos[3 * e0 + 2] - pos[3 * e1 + 2];
    float n0x = normal[3 * e0], n0y = normal[3 * e0 + 1], n0z = normal[3 * e0 + 2];
    float n1x = normal[3 * e1], n1y = normal[3 * e1 + 1], n1z = normal[3 * e1 + 2];
    float d  = sqrtf(px * px + py * py + pz * pz);
    float a1 = angle3(n1x, n1y, n1z, px, py, pz);
    float a2 = angle3(n0x, n0y, n0z, px, py, pz);
    float a3 = angle3(n1x, n1y, n1z, n0x, n0y, n0z);
    uint4 rec;
    rec.x = (unsigned)e0;
    rec.y = pk(d, a1);
    rec.z = pk(a2, a3);
    rec.w = 0;
    prec[p] = rec;
}

__device__ __forceinline__ void load_af(uint4 rec, const unsigned short* __restrict__ xbf,
                                        int quad, short8& a0, short8& a1, short8& a2) {
    const short8* xr = (const short8*)(xbf + (size_t)rec.x * F_DIM);
    a0 = xr[quad];          // k = quad*8 .. +8
    a1 = xr[4 + quad];      // k = 32 + quad*8 .. +8
    short8 z = (short8){0, 0, 0, 0, 0, 0, 0, 0};
    if (quad == 0) {        // k = 64..67 = ppf, 68..71 zero (wt2 rows 68+ are zero anyway)
        z[0] = (short)(rec.y & 0xffff); z[1] = (short)(rec.y >> 16);
        z[2] = (short)(rec.z & 0xffff); z[3] = (short)(rec.z >> 16);
    }
    a2 = z;
}

// wave-per-segment: A from prec/xbf (no conversion, no trig), W2 in LDS staged once/block,
// software-pipelined tile loop, out row = relu(c + max) RMW (c written by cmat).
// __launch_bounds__(256,2): VGPR ~88 regime, NO spills (256,4 capped to 64 VGPR and spilled
// the accumulators -> 195 MB scratch writes, 2.2x slower. R6 lesson.)
__global__ __launch_bounds__(256, 2)
void seg_kernel(const unsigned short* __restrict__ xbf, const unsigned short* __restrict__ wt2,
                const uint4* __restrict__ prec, const int* __restrict__ off,
                const int* __restrict__ ns, float* __restrict__ out, int S) {
    __shared__ __align__(16) unsigned short w_lds[H_DIM * LW2];
    {
        const uint4* src = (const uint4*)wt2;
        uint4* dst = (uint4*)w_lds;
        for (int g = threadIdx.x; g < H_DIM * LW2 / 8; g += 256) dst[g] = src[g];
    }
    __syncthreads();

    const int tid  = threadIdx.x;
    const int wv   = tid >> 6;
    const int lane = tid & 63;
    const int l15  = lane & 15;
    const int quad = lane >> 4;
    const int nw   = gridDim.x << 2;

    for (int s = (blockIdx.x << 2) + wv; s < S; s += nw) {
        const int n = ns[s];
        float* orow = out + (size_t)s * H_DIM;
        if (n == 0) {                   // empty segment or non-canonical duplicate slot
            orow[lane] = 0.f;
            orow[64 + lane] = 0.f;
            continue;
        }
        const uint4* pb = prec + off[s];

        float rm[8];
        #pragma unroll
        for (int ct = 0; ct < 8; ++ct) rm[ct] = -FLT_MAX;

        const int ntile = (n + 15) >> 4;
        int r = l15; if (r >= n) r = n - 1;           // pad rows = real edge dup -> exact for max
        uint4 rec = pb[r];
        short8 a0c, a1c, a2c;
        load_af(rec, xbf, quad, a0c, a1c, a2c);

        for (int t = 0; t < ntile; ++t) {
            // prefetch next tile's record + A-frags (overlaps the MFMAs below)
            uint4 recn = rec;
            if (t + 1 < ntile) {
                int rn = ((t + 1) << 4) + l15; if (rn >= n) rn = n - 1;
                recn = pb[rn];
            }
            short8 a0n, a1n, a2n;
            load_af(recn, xbf, quad, a0n, a1n, a2n);

            f32x4 acc[8];
            #pragma unroll
            for (int ct = 0; ct < 8; ++ct) acc[ct] = (f32x4){0.f, 0.f, 0.f, 0.f};
            #pragma unroll
            for (int ct = 0; ct < 8; ++ct) {
                const unsigned short* wc = w_lds + (ct * 16 + l15) * LW2 + (quad << 3);
                short8 b0 = *(const short8*)(wc);
                short8 b1 = *(const short8*)(wc + 32);
                short8 b2 = *(const short8*)(wc + 64);
                acc[ct] = __builtin_amdgcn_mfma_f32_16x16x32_bf16(a0c, b0, acc[ct], 0, 0, 0);
                acc[ct] = __builtin_amdgcn_mfma_f32_16x16x32_bf16(a1c, b1, acc[ct], 0, 0, 0);
                acc[ct] = __builtin_amdgcn_mfma_f32_16x16x32_bf16(a2c, b2, acc[ct], 0, 0, 0);
            }
            #pragma unroll
            for (int ct = 0; ct < 8; ++ct)
                rm[ct] = fmaxf(rm[ct], fmaxf(fmaxf(acc[ct][0], acc[ct][1]),
                                             fmaxf(acc[ct][2], acc[ct][3])));
            a0c = a0n; a1c = a1n; a2c = a2n; rec = recn;
        }

        #pragma unroll
        for (int ct = 0; ct < 8; ++ct) {
            rm[ct] = fmaxf(rm[ct], __shfl_xor(rm[ct], 16, 64));
            rm[ct] = fmaxf(rm[ct], __shfl_xor(rm[ct], 32, 64));
        }
        float v0 = rm[0], v1 = rm[4];   // col = ct*16 + l15; lane writes cols lane, lane+64
        if (quad == 1)      { v0 = rm[1]; v1 = rm[5]; }
        else if (quad == 2) { v0 = rm[2]; v1 = rm[6]; }
        else if (quad == 3) { v0 = rm[3]; v1 = rm[7]; }
        orow[lane]      = fmaxf(orow[lane] + v0, 0.f);        // c + max, relu (hoist exact)
        orow[64 + lane] = fmaxf(orow[64 + lane] + v1, 0.f);
    }
}

// duplicate-idx fixup only (pos tail handled by prep0)
__global__ void finalize(const int* __restrict__ idx, const int* __restrict__ node2slot,
                         float* __restrict__ out, int S) {
    int g = blockIdx.x * blockDim.x + threadIdx.x;
    if (g >= S * H_DIM) return;
    int s = g >> 7, c = g & 127;
    int sp = node2slot[idx[s]];
    if (sp != s) out[g] = out[(size_t)sp * H_DIM + c];
}

extern "C" void kernel_launch(void* const* d_in, const int* in_sizes, int n_in,
                              void* d_out, int out_size, void* d_ws, size_t ws_size,
                              hipStream_t stream) {
    const float* x      = (const float*)d_in[0];
    const float* pos    = (const float*)d_in[1];
    const float* normal = (const float*)d_in[2];
    const float* W      = (const float*)d_in[3];
    const float* b      = (const float*)d_in[4];
    const int*   edge   = (const int*)d_in[5];
    const int*   idx    = (const int*)d_in[6];

    const int H = in_sizes[4];            // 128
    const int K = in_sizes[3] / H;        // 132
    const int F = (K - 4) / 2;            // 64
    const int N = in_sizes[0] / F;        // 100000
    const int E = in_sizes[5] / 2;        // 800000
    const int S = in_sizes[6];            // 25000

    // ws (256B aligned): wt2 | w1t | xbf[N*64]bf16 | prec[E]uint4 | node2slot[N]
    //                    | cnt_node[N+1] (last int = total) | rank16[E] | off[S] | ns[S]
    char* p = (char*)d_ws;
    auto alloc = [&](size_t bytes) { char* r = p; p += (bytes + 255) & ~(size_t)255; return r; };
    unsigned short* wt2 = (unsigned short*)alloc((size_t)H_DIM * LW2 * sizeof(unsigned short));
    unsigned short* w1t = (unsigned short*)alloc((size_t)H_DIM * LW1 * sizeof(unsigned short));
    unsigned short* xbf = (unsigned short*)alloc((size_t)N * F_DIM * sizeof(unsigned short));
    uint4* prec         = (uint4*)alloc((size_t)E * sizeof(uint4));
    int* node2slot      = (int*)alloc((size_t)N * sizeof(int));
    int* cnt_node       = (int*)alloc((size_t)(N + 1) * sizeof(int));
    unsigned short* rank16 = (unsigned short*)alloc((size_t)E * sizeof(unsigned short));
    int* off            = (int*)alloc((size_t)S * sizeof(int));
    int* ns             = (int*)alloc((size_t)S * sizeof(int));
    float* out = (float*)d_out;           // cmat writes c, seg RMWs to final result

    const int AB = (S + 255) / 256;
    const int CB = (S + 63) / 64;
    const int NF8 = N * F_DIM / 8;

    hipMemsetAsync(cnt_node, 0, (size_t)(N + 1) * sizeof(int), stream);
    prep0<<<1024, 256, 0, stream>>>(W, wt2, w1t, x, xbf, idx, node2slot, edge,
                                    cnt_node, rank16, pos, out, S, E, NF8);
    alloc_cmat<<<AB + CB, 256, 0, stream>>>(cnt_node, node2slot, off, ns, cnt_node + N,
                                            xbf, w1t, b, idx, out, S, AB);
    place_kernel<<<(E + 255) / 256, 256, 0, stream>>>(edge, pos, normal, node2slot,
                                                      rank16, off, prec, E);
    seg_kernel<<<2048, 256, 0, stream>>>(xbf, wt2, prec, off, ns, out, S);
    finalize<<<(S * H + 255) / 256, 256, 0, stream>>>(idx, node2slot, out, S);
}